// Round 16
// baseline (321.176 us; speedup 1.0000x reference)
//
#include <hip/hip_runtime.h>
#include <cstdint>
#include <cstddef>

#define BB 32
#define NN 24564
#define CC 81
#define CM1 80
#define KTOP 100
#define MAXDET 100
#define CBINS 28          // fallback/nms selection bins over (0.0078, 1]
#define CSHIFT 21
#define BASEBITS 0x3C000000u
#define SPECBITS 0x3D400000u   // 0.046875f boundary
#define SPECPF   0.0468281f    // SPEC * 0.999 proxy prefilter (rcp err ~3e-7)
#define CAP2 2048
#define CAPB 25           // per-block per-class spec buffer
#define BPI 96            // blocks per image, 256 rows each
#define CAPS 1024         // nms compacted-selection capacity
#define FCH 8
#define FCHN 1000
#define FPAD 1024

typedef unsigned long long ull;
typedef unsigned int uint;
typedef float floatx4 __attribute__((ext_vector_type(4)));
typedef floatx4 uf4 __attribute__((aligned(4)));   // rows are only 4B-aligned

// ---- pass 0: zero ccnt/ovf (5120 words) ----
__global__ __launch_bounds__(256) void zero_kernel(uint* __restrict__ p, int nwords) {
    int i = blockIdx.x * 256 + threadIdx.x;
    if (i < nwords) p[i] = 0u;
}

// ---- pass 1: single-read register rows; exact softmax stats; spec collect ONLY ----
// launch_bounds(256,4): VGPR cap 128 -> r[81]+temps fit with NO spill at 4 waves/SIMD (50% occ).
// (R15 used (256,2): cap 256, 2 waves/SIMD = 25% occ. R11 default: cap ~64, heavy scratch spill.)
__global__ __launch_bounds__(256, 4) void softmax_spec_kernel(const float* __restrict__ conf,
                                                              float2* __restrict__ mxs,
                                                              ull* __restrict__ cand,
                                                              uint* __restrict__ ccnt,
                                                              uint* __restrict__ ovf) {
    __shared__ ull  sbuf[CM1 * CAPB];    // 16000 B
    __shared__ uint scnt[CM1];           // spec counts per class (this block)
    int tid = threadIdx.x;
    if (tid < CM1) scnt[tid] = 0u;
    __syncthreads();

    int b = blockIdx.x / BPI, j = blockIdx.x % BPI;
    int n = j * 256 + tid;
    if (n < NN) {
        const float* row = conf + ((size_t)b * NN + n) * CC;
        const uf4* row4 = reinterpret_cast<const uf4*>(row);
        float r[CC];
        #pragma unroll
        for (int q = 0; q < 20; ++q) {
            floatx4 v = row4[q];
            r[4 * q] = v.x; r[4 * q + 1] = v.y; r[4 * q + 2] = v.z; r[4 * q + 3] = v.w;
        }
        r[80] = row[80];

        float mx = r[0];
        #pragma unroll
        for (int c = 1; c < CC; ++c) mx = fmaxf(mx, r[c]);   // max: order-independent, exact

        float s = 0.f;                                        // exact sequential sum, c = 0..80
        #pragma unroll
        for (int c = 0; c < CC; ++c) {
            r[c] = expf(__fsub_rn(r[c], mx));
            s = __fadd_rn(s, r[c]);
        }
        mxs[(size_t)b * NN + n] = make_float2(mx, s);

        float rcp = __builtin_amdgcn_rcpf(s);
        uint nn = (uint)n;
        #pragma unroll
        for (int c = 1; c < CC; ++c) {
            float p = __fmul_rn(r[c], rcp);
            if (p > SPECPF) {                      // ~1.5% of elements
                float sc = __fdiv_rn(r[c], s);     // exact score bits
                uint eb = __float_as_uint(sc);
                if (eb >= SPECBITS) {
                    uint pp = atomicAdd(&scnt[c - 1], 1u);
                    if (pp < CAPB) sbuf[(c - 1) * CAPB + pp] = (((ull)(~eb)) << 32) | nn;
                }
            }
        }
    }
    __syncthreads();

    // flush spec buffers: one global atomic per class per block, then coalesced copy
    if (tid < CM1) {
        uint c2 = scnt[tid];
        if (c2) {
            int bc = b * CM1 + tid;
            uint nstore = c2 > CAPB ? CAPB : c2;
            uint base = atomicAdd(ccnt + bc, nstore);
            if (c2 > CAPB || base + nstore > CAP2) ovf[bc] = 1u;
            uint lim = base + nstore; if (lim > CAP2) lim = CAP2;
            for (uint i = 0; base + i < lim; ++i)
                cand[(size_t)bc * CAP2 + base + i] = sbuf[tid * CAPB + i];
        }
    }
}

// ---- pass 2: sufficiency flag per (b,c): >=100 spec members, untruncated => provably complete ----
__global__ __launch_bounds__(256) void flag_kernel(const uint* __restrict__ ccnt,
                                                   const uint* __restrict__ ovf,
                                                   uint* __restrict__ flags) {
    int i = blockIdx.x * 256 + threadIdx.x;
    if (i < BB * CM1)
        flags[i] = (ovf[i] == 0u && ccnt[i] >= (uint)KTOP) ? 0u : 1u;
}

// ---- pass 3 (rare): exact self-contained re-collect for flagged classes ----
__global__ __launch_bounds__(256) void fallback_kernel(const float* __restrict__ conf,
                                                       const float2* __restrict__ mxs,
                                                       const uint* __restrict__ flags,
                                                       ull* __restrict__ cand,
                                                       uint* __restrict__ ccnt) {
    int bc = blockIdx.x;
    if (flags[bc] == 0u) return;
    int b = bc / CM1, c = bc % CM1 + 1;
    __shared__ uint hist[CBINS];
    __shared__ uint s_cut, lcnt;
    int tid = threadIdx.x;
    for (int i = tid; i < CBINS; i += 256) hist[i] = 0u;
    if (tid == 0) { s_cut = 0xFFFFFFFFu; lcnt = 0u; }
    __syncthreads();

    for (int n = tid; n < NN; n += 256) {
        float x = conf[((size_t)b * NN + n) * CC + c];
        float2 ms = mxs[(size_t)b * NN + n];
        float e = expf(__fsub_rn(x, ms.x));
        float sc = __fdiv_rn(e, ms.y);
        if (sc > 0.01f) {
            uint bits = __float_as_uint(sc);
            uint bin = (bits - BASEBITS) >> CSHIFT;
            if (bin >= CBINS) bin = CBINS - 1;
            atomicAdd(&hist[bin], 1u);
        }
    }
    __syncthreads();
    if (tid == 0) {
        uint total = 0;
        for (int i = 0; i < CBINS; ++i) total += hist[i];
        uint Kt = total < KTOP ? total : KTOP;
        if (Kt > 0) {
            uint cum = 0; int bb2 = 0;
            for (int i = CBINS - 1; i >= 0; --i) {
                cum += hist[i];
                if (cum >= Kt) { bb2 = i; break; }
            }
            uint cutbin = (cum <= CAP2) ? (uint)bb2 : (uint)(bb2 + 1);
            s_cut = BASEBITS + (cutbin << CSHIFT);
        }
    }
    __syncthreads();
    uint cutv = s_cut;

    for (int n = tid; n < NN; n += 256) {
        float x = conf[((size_t)b * NN + n) * CC + c];
        float2 ms = mxs[(size_t)b * NN + n];
        float e = expf(__fsub_rn(x, ms.x));
        float sc = __fdiv_rn(e, ms.y);
        if (sc > 0.01f) {
            uint bits = __float_as_uint(sc);
            if (bits >= cutv) {
                uint p = atomicAdd(&lcnt, 1u);
                if (p < CAP2)
                    cand[(size_t)bc * CAP2 + p] = (((ull)(~bits)) << 32) | (uint)n;
            }
        }
    }
    __syncthreads();
    if (tid == 0) ccnt[bc] = (lcnt < CAP2) ? lcnt : CAP2;
}

// ---- pass 4: per-(b,c) in-kernel rank-Kt cut + compact + sort + fused decode + greedy NMS ----
__global__ __launch_bounds__(256) void nms_kernel(const ull* __restrict__ cand,
                                                  const uint* __restrict__ ccnt,
                                                  const float* __restrict__ loc,
                                                  const float* __restrict__ priors,
                                                  float* __restrict__ nms_scores,
                                                  float* __restrict__ nms_boxes) {
    int bc = blockIdx.x;
    int bimg = bc / CM1;
    __shared__ ull arr[CAP2];                 // 16 KB (full-list fallback sort space)
    __shared__ ull arr2[CAPS];                // 8 KB (compacted selection)
    __shared__ uint hist[CBINS];
    __shared__ uint s_cut, s_mode, s_cnt2;
    __shared__ float bx[KTOP][4];
    __shared__ float sv[KTOP];
    __shared__ ull mlo[KTOP], mhi[KTOP];
    __shared__ ull keeplo, keephi;

    int tid = threadIdx.x;
    for (int i = tid; i < CBINS; i += 256) hist[i] = 0u;
    if (tid == 0) { s_cut = 0u; s_mode = 0u; s_cnt2 = 0u; }
    __syncthreads();

    int cc = (int)ccnt[bc]; if (cc > CAP2) cc = CAP2;
    const ull* crow = cand + (size_t)bc * CAP2;
    for (int i = tid; i < cc; i += 256) {
        ull k = crow[i];
        arr[i] = k;
        uint bits = ~(uint)(k >> 32);
        uint bin = (bits - BASEBITS) >> CSHIFT;
        if (bin >= CBINS) bin = CBINS - 1;
        atomicAdd(&hist[bin], 1u);
    }
    __syncthreads();
    if (tid == 0) {
        uint Kt = (uint)(cc < KTOP ? cc : KTOP);
        if (Kt > 0) {
            uint cum = 0; int bb2 = 0;
            for (int i = CBINS - 1; i >= 0; --i) {
                cum += hist[i];
                if (cum >= Kt) { bb2 = i; break; }
            }
            if (cum <= CAPS) {              // selection fits the small buffer
                s_cut = BASEBITS + ((uint)bb2 << CSHIFT);
                s_mode = 1u;
            }
        }
    }
    __syncthreads();

    int scc; ull* sorted;
    if (s_mode) {
        uint cutv = s_cut;
        for (int i = tid; i < cc; i += 256) {
            ull k = arr[i];
            uint bits = ~(uint)(k >> 32);
            if (bits >= cutv) { uint p = atomicAdd(&s_cnt2, 1u); arr2[p] = k; }
        }
        __syncthreads();
        scc = (int)s_cnt2;
        sorted = arr2;
    } else {
        scc = cc;
        sorted = arr;
    }
    int S = 1; while (S < scc) S <<= 1; if (S < 2) S = 2;
    for (int i = scc + tid; i < S; i += 256) sorted[i] = ~0ull;
    __syncthreads();

    for (int k = 2; k <= S; k <<= 1) {
        for (int jj = k >> 1; jj > 0; jj >>= 1) {
            for (int i = tid; i < S; i += 256) {
                int ixj = i ^ jj;
                if (ixj > i) {
                    ull a = sorted[i], b2 = sorted[ixj];
                    bool up = ((i & k) == 0);
                    if ((a > b2) == up) { sorted[i] = b2; sorted[ixj] = a; }
                }
            }
            __syncthreads();
        }
    }

    if (tid < KTOP) {
        float val = 0.f; uint n = 0;
        if (tid < scc) {
            ull kk = sorted[tid];
            val = __uint_as_float(~(uint)(kk >> 32));
            n = (uint)(kk & 0xFFFFFFFFu);
        }
        sv[tid] = val;
        float4 l = reinterpret_cast<const float4*>(loc)[(size_t)bimg * NN + n];
        float4 p = reinterpret_cast<const float4*>(priors)[n];
        float cx = __fadd_rn(__fmul_rn(__fmul_rn(l.x, 0.1f), p.z), p.x);
        float cy = __fadd_rn(__fmul_rn(__fmul_rn(l.y, 0.1f), p.w), p.y);
        float w  = __fmul_rn(expf(__fmul_rn(l.z, 0.2f)), p.z);
        float h  = __fmul_rn(expf(__fmul_rn(l.w, 0.2f)), p.w);
        bx[tid][0] = __fsub_rn(cx, __fmul_rn(w, 0.5f));
        bx[tid][1] = __fsub_rn(cy, __fmul_rn(h, 0.5f));
        bx[tid][2] = __fadd_rn(cx, __fmul_rn(w, 0.5f));
        bx[tid][3] = __fadd_rn(cy, __fmul_rn(h, 0.5f));
    }
    __syncthreads();

    if (tid < KTOP) {
        float x1 = bx[tid][0], y1 = bx[tid][1], x2 = bx[tid][2], y2 = bx[tid][3];
        float ai = __fmul_rn(fmaxf(__fsub_rn(x2, x1), 0.f), fmaxf(__fsub_rn(y2, y1), 0.f));
        ull lo = 0, hi = 0;
        for (int jj = 0; jj < KTOP; ++jj) {
            float jx1 = bx[jj][0], jy1 = bx[jj][1], jx2 = bx[jj][2], jy2 = bx[jj][3];
            float iw = fmaxf(__fsub_rn(fminf(x2, jx2), fmaxf(x1, jx1)), 0.f);
            float ih = fmaxf(__fsub_rn(fminf(y2, jy2), fmaxf(y1, jy1)), 0.f);
            float inter = __fmul_rn(iw, ih);
            float aj = __fmul_rn(fmaxf(__fsub_rn(jx2, jx1), 0.f), fmaxf(__fsub_rn(jy2, jy1), 0.f));
            float denom = __fadd_rn(__fsub_rn(__fadd_rn(ai, aj), inter), 1e-8f);
            float iou = __fdiv_rn(inter, denom);
            if (iou > 0.45f) { if (jj < 64) lo |= (1ull << jj); else hi |= (1ull << (jj - 64)); }
        }
        mlo[tid] = lo; mhi[tid] = hi;
    }
    __syncthreads();

    if (tid == 0) {
        ull klo = 0, khi = 0;
        for (int i = 0; i < KTOP; ++i) {
            ull sup = (mlo[i] & klo) | (mhi[i] & khi);
            bool kp = (sv[i] > 0.f) && (sup == 0ull);
            if (kp) { if (i < 64) klo |= (1ull << i); else khi |= (1ull << (i - 64)); }
        }
        keeplo = klo; keephi = khi;
    }
    __syncthreads();

    if (tid < KTOP) {
        bool kp = (tid < 64) ? ((keeplo >> tid) & 1ull) : ((keephi >> (tid - 64)) & 1ull);
        size_t obase = (size_t)bc * KTOP + tid;
        nms_scores[obase] = kp ? sv[tid] : 0.f;
        float4 o; o.x = bx[tid][0]; o.y = bx[tid][1]; o.z = bx[tid][2]; o.w = bx[tid][3];
        reinterpret_cast<float4*>(nms_boxes)[obase] = o;
    }
}

// ---- final top-100, stage A: per-(image,chunk) top-100 of 1000 ----
__global__ __launch_bounds__(256) void final_partial_kernel(const float* __restrict__ nms_scores,
                                                            ull* __restrict__ fkeys) {
    int blk = blockIdx.x;             // b*FCH + ch
    int b = blk / FCH, ch = blk % FCH;
    __shared__ ull arr[FPAD];         // 8 KB
    int tid = threadIdx.x;
    const float* srow = nms_scores + (size_t)b * (CM1 * KTOP) + ch * FCHN;
    for (int i = tid; i < FPAD; i += 256) {
        ull key;
        if (i < FCHN) {
            float s = srow[i];
            uint bits = (s > 0.f) ? __float_as_uint(s) : 0u;
            key = (((ull)(~bits)) << 32) | (uint)(ch * FCHN + i);   // global per-image idx
        } else key = ~0ull;
        arr[i] = key;
    }
    __syncthreads();
    for (int k = 2; k <= FPAD; k <<= 1) {
        for (int jj = k >> 1; jj > 0; jj >>= 1) {
            for (int i = tid; i < FPAD; i += 256) {
                int ixj = i ^ jj;
                if (ixj > i) {
                    ull a = arr[i], b2 = arr[ixj];
                    bool up = ((i & k) == 0);
                    if ((a > b2) == up) { arr[i] = b2; arr[ixj] = a; }
                }
            }
            __syncthreads();
        }
    }
    if (tid < KTOP)
        fkeys[(size_t)b * (FCH * KTOP) + ch * KTOP + tid] = arr[tid];
}

// ---- final top-100, stage B: merge 8x100 -> exact top-100, gather ----
__global__ __launch_bounds__(256) void final_merge_kernel(const ull* __restrict__ fkeys,
                                                          const float* __restrict__ nms_boxes,
                                                          float* __restrict__ out) {
    int b = blockIdx.x;
    __shared__ ull arr[FPAD];         // 8 KB
    int tid = threadIdx.x;
    const ull* krow = fkeys + (size_t)b * (FCH * KTOP);
    for (int i = tid; i < FPAD; i += 256)
        arr[i] = (i < FCH * KTOP) ? krow[i] : ~0ull;
    __syncthreads();
    for (int k = 2; k <= FPAD; k <<= 1) {
        for (int jj = k >> 1; jj > 0; jj >>= 1) {
            for (int i = tid; i < FPAD; i += 256) {
                int ixj = i ^ jj;
                if (ixj > i) {
                    ull a = arr[i], b2 = arr[ixj];
                    bool up = ((i & k) == 0);
                    if ((a > b2) == up) { arr[i] = b2; arr[ixj] = a; }
                }
            }
            __syncthreads();
        }
    }
    if (tid < MAXDET) {
        ull kk = arr[tid];
        uint hb = (uint)(kk >> 32);
        uint idx = (uint)(kk & 0xFFFFFFFFu);
        float val = __uint_as_float(~hb);     // zeros decode to 0.0f
        float4 b4 = reinterpret_cast<const float4*>(nms_boxes)[(size_t)b * (CM1 * KTOP) + idx];
        reinterpret_cast<float4*>(out)[(size_t)b * MAXDET + tid] = b4;
        out[BB * MAXDET * 4 + b * MAXDET + tid] = val;
        out[BB * MAXDET * 5 + b * MAXDET + tid] = (float)(idx / KTOP + 1);
    }
}

extern "C" void kernel_launch(void* const* d_in, const int* in_sizes, int n_in,
                              void* d_out, int out_size, void* d_ws, size_t ws_size,
                              hipStream_t stream) {
    const float* loc    = (const float*)d_in[0];
    const float* conf   = (const float*)d_in[1];
    const float* priors = (const float*)d_in[2];
    float* out = (float*)d_out;

    // workspace layout (16B-aligned chunks); ccnt/ovf are the zeroed pair (contiguous)
    char* ws = (char*)d_ws;
    float* nms_scores = (float*)ws;                                        // 1.02 MB
    float* nms_boxes  = nms_scores + (size_t)BB * CM1 * KTOP;              // 4.1 MB
    ull*   cand       = (ull*)(nms_boxes + (size_t)BB * CM1 * KTOP * 4);   // 41.9 MB
    float2* mxs       = (float2*)(cand + (size_t)BB * CM1 * CAP2);         // 6.3 MB
    ull*   fkeys      = (ull*)(mxs + (size_t)BB * NN);                     // 0.2 MB
    uint*  flags      = (uint*)(fkeys + (size_t)BB * FCH * KTOP);          // 2560 (always written)
    uint*  ccnt       = flags + (size_t)BB * CM1;                          // 2560 zeroed
    uint*  ovf        = ccnt + (size_t)BB * CM1;                           // 2560 zeroed

    zero_kernel<<<(BB * CM1 * 2 + 255) / 256, 256, 0, stream>>>(ccnt, BB * CM1 * 2);

    softmax_spec_kernel<<<BB * BPI, 256, 0, stream>>>(conf, mxs, cand, ccnt, ovf);
    flag_kernel<<<(BB * CM1 + 255) / 256, 256, 0, stream>>>(ccnt, ovf, flags);
    fallback_kernel<<<BB * CM1, 256, 0, stream>>>(conf, mxs, flags, cand, ccnt);
    nms_kernel<<<BB * CM1, 256, 0, stream>>>(cand, ccnt, loc, priors, nms_scores, nms_boxes);
    final_partial_kernel<<<BB * FCH, 256, 0, stream>>>(nms_scores, fkeys);
    final_merge_kernel<<<BB, 256, 0, stream>>>(fkeys, nms_boxes, out);
}

// Round 17
// 320.886 us; speedup vs baseline: 1.0009x; 1.0009x over previous
//
#include <hip/hip_runtime.h>
#include <cstdint>
#include <cstddef>

#define BB 32
#define NN 24564
#define CC 81
#define CM1 80
#define KTOP 100
#define MAXDET 100
#define CBINS 28          // fallback/nms selection bins over (0.0078, 1]
#define CSHIFT 21
#define BASEBITS 0x3C000000u
#define SPECBITS 0x3D400000u   // 0.046875f boundary
#define SPECPF   0.0468281f    // SPEC * 0.999 proxy prefilter (rcp err ~3e-7)
#define CAP2 2048
#define CAPB 25           // per-block per-class spec buffer
#define BPI 96            // blocks per image, 256 rows each
#define CAPS 1024         // nms compacted-selection capacity
#define FCH 8
#define FCHN 1000
#define FPAD 1024

typedef unsigned long long ull;
typedef unsigned int uint;
typedef float floatx4 __attribute__((ext_vector_type(4)));
typedef floatx4 uf4 __attribute__((aligned(4)));   // rows are only 4B-aligned

// ---- pass 0: zero ccnt/ovf (5120 words) ----
__global__ __launch_bounds__(256) void zero_kernel(uint* __restrict__ p, int nwords) {
    int i = blockIdx.x * 256 + threadIdx.x;
    if (i < nwords) p[i] = 0u;
}

// ---- pass 1: single-read register rows; exact softmax stats; spec collect ONLY ----
// DEFAULT launch bounds: compiler picks low VGPR (~48, r[81] partially spilled) but occupancy
// stays high (~50%+) — empirically the fastest regime for this latency-bound strided load
// (R11 at default beat both clamped variants R15/R16).
__global__ __launch_bounds__(256) void softmax_spec_kernel(const float* __restrict__ conf,
                                                           float2* __restrict__ mxs,
                                                           ull* __restrict__ cand,
                                                           uint* __restrict__ ccnt,
                                                           uint* __restrict__ ovf) {
    __shared__ ull  sbuf[CM1 * CAPB];    // 16000 B
    __shared__ uint scnt[CM1];           // spec counts per class (this block)
    int tid = threadIdx.x;
    if (tid < CM1) scnt[tid] = 0u;
    __syncthreads();

    int b = blockIdx.x / BPI, j = blockIdx.x % BPI;
    int n = j * 256 + tid;
    if (n < NN) {
        const float* row = conf + ((size_t)b * NN + n) * CC;
        const uf4* row4 = reinterpret_cast<const uf4*>(row);
        float r[CC];
        #pragma unroll
        for (int q = 0; q < 20; ++q) {
            floatx4 v = row4[q];
            r[4 * q] = v.x; r[4 * q + 1] = v.y; r[4 * q + 2] = v.z; r[4 * q + 3] = v.w;
        }
        r[80] = row[80];

        float mx = r[0];
        #pragma unroll
        for (int c = 1; c < CC; ++c) mx = fmaxf(mx, r[c]);   // max: order-independent, exact

        float s = 0.f;                                        // exact sequential sum, c = 0..80
        #pragma unroll
        for (int c = 0; c < CC; ++c) {
            r[c] = expf(__fsub_rn(r[c], mx));
            s = __fadd_rn(s, r[c]);
        }
        mxs[(size_t)b * NN + n] = make_float2(mx, s);

        float rcp = __builtin_amdgcn_rcpf(s);
        uint nn = (uint)n;
        #pragma unroll
        for (int c = 1; c < CC; ++c) {
            float p = __fmul_rn(r[c], rcp);
            if (p > SPECPF) {                      // ~1.5% of elements
                float sc = __fdiv_rn(r[c], s);     // exact score bits
                uint eb = __float_as_uint(sc);
                if (eb >= SPECBITS) {
                    uint pp = atomicAdd(&scnt[c - 1], 1u);
                    if (pp < CAPB) sbuf[(c - 1) * CAPB + pp] = (((ull)(~eb)) << 32) | nn;
                }
            }
        }
    }
    __syncthreads();

    // flush spec buffers: one global atomic per class per block, then coalesced copy
    if (tid < CM1) {
        uint c2 = scnt[tid];
        if (c2) {
            int bc = b * CM1 + tid;
            uint nstore = c2 > CAPB ? CAPB : c2;
            uint base = atomicAdd(ccnt + bc, nstore);
            if (c2 > CAPB || base + nstore > CAP2) ovf[bc] = 1u;
            uint lim = base + nstore; if (lim > CAP2) lim = CAP2;
            for (uint i = 0; base + i < lim; ++i)
                cand[(size_t)bc * CAP2 + base + i] = sbuf[tid * CAPB + i];
        }
    }
}

// ---- pass 2: sufficiency flag per (b,c): >=100 spec members, untruncated => provably complete ----
__global__ __launch_bounds__(256) void flag_kernel(const uint* __restrict__ ccnt,
                                                   const uint* __restrict__ ovf,
                                                   uint* __restrict__ flags) {
    int i = blockIdx.x * 256 + threadIdx.x;
    if (i < BB * CM1)
        flags[i] = (ovf[i] == 0u && ccnt[i] >= (uint)KTOP) ? 0u : 1u;
}

// ---- pass 3 (rare): exact self-contained re-collect for flagged classes ----
__global__ __launch_bounds__(256) void fallback_kernel(const float* __restrict__ conf,
                                                       const float2* __restrict__ mxs,
                                                       const uint* __restrict__ flags,
                                                       ull* __restrict__ cand,
                                                       uint* __restrict__ ccnt) {
    int bc = blockIdx.x;
    if (flags[bc] == 0u) return;
    int b = bc / CM1, c = bc % CM1 + 1;
    __shared__ uint hist[CBINS];
    __shared__ uint s_cut, lcnt;
    int tid = threadIdx.x;
    for (int i = tid; i < CBINS; i += 256) hist[i] = 0u;
    if (tid == 0) { s_cut = 0xFFFFFFFFu; lcnt = 0u; }
    __syncthreads();

    for (int n = tid; n < NN; n += 256) {
        float x = conf[((size_t)b * NN + n) * CC + c];
        float2 ms = mxs[(size_t)b * NN + n];
        float e = expf(__fsub_rn(x, ms.x));
        float sc = __fdiv_rn(e, ms.y);
        if (sc > 0.01f) {
            uint bits = __float_as_uint(sc);
            uint bin = (bits - BASEBITS) >> CSHIFT;
            if (bin >= CBINS) bin = CBINS - 1;
            atomicAdd(&hist[bin], 1u);
        }
    }
    __syncthreads();
    if (tid == 0) {
        uint total = 0;
        for (int i = 0; i < CBINS; ++i) total += hist[i];
        uint Kt = total < KTOP ? total : KTOP;
        if (Kt > 0) {
            uint cum = 0; int bb2 = 0;
            for (int i = CBINS - 1; i >= 0; --i) {
                cum += hist[i];
                if (cum >= Kt) { bb2 = i; break; }
            }
            uint cutbin = (cum <= CAP2) ? (uint)bb2 : (uint)(bb2 + 1);
            s_cut = BASEBITS + (cutbin << CSHIFT);
        }
    }
    __syncthreads();
    uint cutv = s_cut;

    for (int n = tid; n < NN; n += 256) {
        float x = conf[((size_t)b * NN + n) * CC + c];
        float2 ms = mxs[(size_t)b * NN + n];
        float e = expf(__fsub_rn(x, ms.x));
        float sc = __fdiv_rn(e, ms.y);
        if (sc > 0.01f) {
            uint bits = __float_as_uint(sc);
            if (bits >= cutv) {
                uint p = atomicAdd(&lcnt, 1u);
                if (p < CAP2)
                    cand[(size_t)bc * CAP2 + p] = (((ull)(~bits)) << 32) | (uint)n;
            }
        }
    }
    __syncthreads();
    if (tid == 0) ccnt[bc] = (lcnt < CAP2) ? lcnt : CAP2;
}

// ---- pass 4: per-(b,c) in-kernel rank-Kt cut + compact + sort + fused decode + greedy NMS ----
__global__ __launch_bounds__(256) void nms_kernel(const ull* __restrict__ cand,
                                                  const uint* __restrict__ ccnt,
                                                  const float* __restrict__ loc,
                                                  const float* __restrict__ priors,
                                                  float* __restrict__ nms_scores,
                                                  float* __restrict__ nms_boxes) {
    int bc = blockIdx.x;
    int bimg = bc / CM1;
    __shared__ ull arr[CAP2];                 // 16 KB (full-list fallback sort space)
    __shared__ ull arr2[CAPS];                // 8 KB (compacted selection)
    __shared__ uint hist[CBINS];
    __shared__ uint s_cut, s_mode, s_cnt2;
    __shared__ float bx[KTOP][4];
    __shared__ float sv[KTOP];
    __shared__ ull mlo[KTOP], mhi[KTOP];
    __shared__ ull keeplo, keephi;

    int tid = threadIdx.x;
    for (int i = tid; i < CBINS; i += 256) hist[i] = 0u;
    if (tid == 0) { s_cut = 0u; s_mode = 0u; s_cnt2 = 0u; }
    __syncthreads();

    int cc = (int)ccnt[bc]; if (cc > CAP2) cc = CAP2;
    const ull* crow = cand + (size_t)bc * CAP2;
    for (int i = tid; i < cc; i += 256) {
        ull k = crow[i];
        arr[i] = k;
        uint bits = ~(uint)(k >> 32);
        uint bin = (bits - BASEBITS) >> CSHIFT;
        if (bin >= CBINS) bin = CBINS - 1;
        atomicAdd(&hist[bin], 1u);
    }
    __syncthreads();
    if (tid == 0) {
        uint Kt = (uint)(cc < KTOP ? cc : KTOP);
        if (Kt > 0) {
            uint cum = 0; int bb2 = 0;
            for (int i = CBINS - 1; i >= 0; --i) {
                cum += hist[i];
                if (cum >= Kt) { bb2 = i; break; }
            }
            if (cum <= CAPS) {              // selection fits the small buffer
                s_cut = BASEBITS + ((uint)bb2 << CSHIFT);
                s_mode = 1u;
            }
        }
    }
    __syncthreads();

    int scc; ull* sorted;
    if (s_mode) {
        uint cutv = s_cut;
        for (int i = tid; i < cc; i += 256) {
            ull k = arr[i];
            uint bits = ~(uint)(k >> 32);
            if (bits >= cutv) { uint p = atomicAdd(&s_cnt2, 1u); arr2[p] = k; }
        }
        __syncthreads();
        scc = (int)s_cnt2;
        sorted = arr2;
    } else {
        scc = cc;
        sorted = arr;
    }
    int S = 1; while (S < scc) S <<= 1; if (S < 2) S = 2;
    for (int i = scc + tid; i < S; i += 256) sorted[i] = ~0ull;
    __syncthreads();

    for (int k = 2; k <= S; k <<= 1) {
        for (int jj = k >> 1; jj > 0; jj >>= 1) {
            for (int i = tid; i < S; i += 256) {
                int ixj = i ^ jj;
                if (ixj > i) {
                    ull a = sorted[i], b2 = sorted[ixj];
                    bool up = ((i & k) == 0);
                    if ((a > b2) == up) { sorted[i] = b2; sorted[ixj] = a; }
                }
            }
            __syncthreads();
        }
    }

    if (tid < KTOP) {
        float val = 0.f; uint n = 0;
        if (tid < scc) {
            ull kk = sorted[tid];
            val = __uint_as_float(~(uint)(kk >> 32));
            n = (uint)(kk & 0xFFFFFFFFu);
        }
        sv[tid] = val;
        float4 l = reinterpret_cast<const float4*>(loc)[(size_t)bimg * NN + n];
        float4 p = reinterpret_cast<const float4*>(priors)[n];
        float cx = __fadd_rn(__fmul_rn(__fmul_rn(l.x, 0.1f), p.z), p.x);
        float cy = __fadd_rn(__fmul_rn(__fmul_rn(l.y, 0.1f), p.w), p.y);
        float w  = __fmul_rn(expf(__fmul_rn(l.z, 0.2f)), p.z);
        float h  = __fmul_rn(expf(__fmul_rn(l.w, 0.2f)), p.w);
        bx[tid][0] = __fsub_rn(cx, __fmul_rn(w, 0.5f));
        bx[tid][1] = __fsub_rn(cy, __fmul_rn(h, 0.5f));
        bx[tid][2] = __fadd_rn(cx, __fmul_rn(w, 0.5f));
        bx[tid][3] = __fadd_rn(cy, __fmul_rn(h, 0.5f));
    }
    __syncthreads();

    if (tid < KTOP) {
        float x1 = bx[tid][0], y1 = bx[tid][1], x2 = bx[tid][2], y2 = bx[tid][3];
        float ai = __fmul_rn(fmaxf(__fsub_rn(x2, x1), 0.f), fmaxf(__fsub_rn(y2, y1), 0.f));
        ull lo = 0, hi = 0;
        for (int jj = 0; jj < KTOP; ++jj) {
            float jx1 = bx[jj][0], jy1 = bx[jj][1], jx2 = bx[jj][2], jy2 = bx[jj][3];
            float iw = fmaxf(__fsub_rn(fminf(x2, jx2), fmaxf(x1, jx1)), 0.f);
            float ih = fmaxf(__fsub_rn(fminf(y2, jy2), fmaxf(y1, jy1)), 0.f);
            float inter = __fmul_rn(iw, ih);
            float aj = __fmul_rn(fmaxf(__fsub_rn(jx2, jx1), 0.f), fmaxf(__fsub_rn(jy2, jy1), 0.f));
            float denom = __fadd_rn(__fsub_rn(__fadd_rn(ai, aj), inter), 1e-8f);
            float iou = __fdiv_rn(inter, denom);
            if (iou > 0.45f) { if (jj < 64) lo |= (1ull << jj); else hi |= (1ull << (jj - 64)); }
        }
        mlo[tid] = lo; mhi[tid] = hi;
    }
    __syncthreads();

    if (tid == 0) {
        ull klo = 0, khi = 0;
        for (int i = 0; i < KTOP; ++i) {
            ull sup = (mlo[i] & klo) | (mhi[i] & khi);
            bool kp = (sv[i] > 0.f) && (sup == 0ull);
            if (kp) { if (i < 64) klo |= (1ull << i); else khi |= (1ull << (i - 64)); }
        }
        keeplo = klo; keephi = khi;
    }
    __syncthreads();

    if (tid < KTOP) {
        bool kp = (tid < 64) ? ((keeplo >> tid) & 1ull) : ((keephi >> (tid - 64)) & 1ull);
        size_t obase = (size_t)bc * KTOP + tid;
        nms_scores[obase] = kp ? sv[tid] : 0.f;
        float4 o; o.x = bx[tid][0]; o.y = bx[tid][1]; o.z = bx[tid][2]; o.w = bx[tid][3];
        reinterpret_cast<float4*>(nms_boxes)[obase] = o;
    }
}

// ---- final top-100, stage A: per-(image,chunk) top-100 of 1000 ----
__global__ __launch_bounds__(256) void final_partial_kernel(const float* __restrict__ nms_scores,
                                                            ull* __restrict__ fkeys) {
    int blk = blockIdx.x;             // b*FCH + ch
    int b = blk / FCH, ch = blk % FCH;
    __shared__ ull arr[FPAD];         // 8 KB
    int tid = threadIdx.x;
    const float* srow = nms_scores + (size_t)b * (CM1 * KTOP) + ch * FCHN;
    for (int i = tid; i < FPAD; i += 256) {
        ull key;
        if (i < FCHN) {
            float s = srow[i];
            uint bits = (s > 0.f) ? __float_as_uint(s) : 0u;
            key = (((ull)(~bits)) << 32) | (uint)(ch * FCHN + i);   // global per-image idx
        } else key = ~0ull;
        arr[i] = key;
    }
    __syncthreads();
    for (int k = 2; k <= FPAD; k <<= 1) {
        for (int jj = k >> 1; jj > 0; jj >>= 1) {
            for (int i = tid; i < FPAD; i += 256) {
                int ixj = i ^ jj;
                if (ixj > i) {
                    ull a = arr[i], b2 = arr[ixj];
                    bool up = ((i & k) == 0);
                    if ((a > b2) == up) { arr[i] = b2; arr[ixj] = a; }
                }
            }
            __syncthreads();
        }
    }
    if (tid < KTOP)
        fkeys[(size_t)b * (FCH * KTOP) + ch * KTOP + tid] = arr[tid];
}

// ---- final top-100, stage B: merge 8x100 -> exact top-100, gather ----
__global__ __launch_bounds__(256) void final_merge_kernel(const ull* __restrict__ fkeys,
                                                          const float* __restrict__ nms_boxes,
                                                          float* __restrict__ out) {
    int b = blockIdx.x;
    __shared__ ull arr[FPAD];         // 8 KB
    int tid = threadIdx.x;
    const ull* krow = fkeys + (size_t)b * (FCH * KTOP);
    for (int i = tid; i < FPAD; i += 256)
        arr[i] = (i < FCH * KTOP) ? krow[i] : ~0ull;
    __syncthreads();
    for (int k = 2; k <= FPAD; k <<= 1) {
        for (int jj = k >> 1; jj > 0; jj >>= 1) {
            for (int i = tid; i < FPAD; i += 256) {
                int ixj = i ^ jj;
                if (ixj > i) {
                    ull a = arr[i], b2 = arr[ixj];
                    bool up = ((i & k) == 0);
                    if ((a > b2) == up) { arr[i] = b2; arr[ixj] = a; }
                }
            }
            __syncthreads();
        }
    }
    if (tid < MAXDET) {
        ull kk = arr[tid];
        uint hb = (uint)(kk >> 32);
        uint idx = (uint)(kk & 0xFFFFFFFFu);
        float val = __uint_as_float(~hb);     // zeros decode to 0.0f
        float4 b4 = reinterpret_cast<const float4*>(nms_boxes)[(size_t)b * (CM1 * KTOP) + idx];
        reinterpret_cast<float4*>(out)[(size_t)b * MAXDET + tid] = b4;
        out[BB * MAXDET * 4 + b * MAXDET + tid] = val;
        out[BB * MAXDET * 5 + b * MAXDET + tid] = (float)(idx / KTOP + 1);
    }
}

extern "C" void kernel_launch(void* const* d_in, const int* in_sizes, int n_in,
                              void* d_out, int out_size, void* d_ws, size_t ws_size,
                              hipStream_t stream) {
    const float* loc    = (const float*)d_in[0];
    const float* conf   = (const float*)d_in[1];
    const float* priors = (const float*)d_in[2];
    float* out = (float*)d_out;

    // workspace layout (16B-aligned chunks); ccnt/ovf are the zeroed pair (contiguous)
    char* ws = (char*)d_ws;
    float* nms_scores = (float*)ws;                                        // 1.02 MB
    float* nms_boxes  = nms_scores + (size_t)BB * CM1 * KTOP;              // 4.1 MB
    ull*   cand       = (ull*)(nms_boxes + (size_t)BB * CM1 * KTOP * 4);   // 41.9 MB
    float2* mxs       = (float2*)(cand + (size_t)BB * CM1 * CAP2);         // 6.3 MB
    ull*   fkeys      = (ull*)(mxs + (size_t)BB * NN);                     // 0.2 MB
    uint*  flags      = (uint*)(fkeys + (size_t)BB * FCH * KTOP);          // 2560 (always written)
    uint*  ccnt       = flags + (size_t)BB * CM1;                          // 2560 zeroed
    uint*  ovf        = ccnt + (size_t)BB * CM1;                           // 2560 zeroed

    zero_kernel<<<(BB * CM1 * 2 + 255) / 256, 256, 0, stream>>>(ccnt, BB * CM1 * 2);

    softmax_spec_kernel<<<BB * BPI, 256, 0, stream>>>(conf, mxs, cand, ccnt, ovf);
    flag_kernel<<<(BB * CM1 + 255) / 256, 256, 0, stream>>>(ccnt, ovf, flags);
    fallback_kernel<<<BB * CM1, 256, 0, stream>>>(conf, mxs, flags, cand, ccnt);
    nms_kernel<<<BB * CM1, 256, 0, stream>>>(cand, ccnt, loc, priors, nms_scores, nms_boxes);
    final_partial_kernel<<<BB * FCH, 256, 0, stream>>>(nms_scores, fkeys);
    final_merge_kernel<<<BB, 256, 0, stream>>>(fkeys, nms_boxes, out);
}

// Round 18
// 270.072 us; speedup vs baseline: 1.1892x; 1.1881x over previous
//
#include <hip/hip_runtime.h>
#include <cstdint>
#include <cstddef>

#define BB 32
#define NN 24564
#define CC 81
#define CM1 80
#define KTOP 100
#define MAXDET 100
#define CBINS 28          // selection bins over (0.0078, 1]
#define CSHIFT 21
#define BASEBITS 0x3C000000u
#define SPECBITS 0x3D400000u   // 0.046875f boundary
#define SPECPF   0.0468281f    // SPEC * 0.999 proxy prefilter (rcp err ~3e-7)
#define CAP2 2048
#define CAPB 25           // per-block per-class spec buffer
#define BPI 96            // blocks per image, 256 rows each
#define CAPS 1024         // nms compacted-selection capacity
#define FCH 8
#define FCHN 1000
#define FPAD 1024

typedef unsigned long long ull;
typedef unsigned int uint;
typedef float floatx4 __attribute__((ext_vector_type(4)));
typedef floatx4 uf4 __attribute__((aligned(4)));   // rows are only 4B-aligned

// ---- pass 0: zero ccnt/ovf (5120 words) ----
__global__ __launch_bounds__(256) void zero_kernel(uint* __restrict__ p, int nwords) {
    int i = blockIdx.x * 256 + threadIdx.x;
    if (i < nwords) p[i] = 0u;
}

// ---- pass 1: single-read register rows; exact softmax stats; spec collect ----
__global__ __launch_bounds__(256) void softmax_spec_kernel(const float* __restrict__ conf,
                                                           float2* __restrict__ mxs,
                                                           ull* __restrict__ cand,
                                                           uint* __restrict__ ccnt,
                                                           uint* __restrict__ ovf) {
    __shared__ ull  sbuf[CM1 * CAPB];    // 16000 B
    __shared__ uint scnt[CM1];           // spec counts per class (this block)
    int tid = threadIdx.x;
    if (tid < CM1) scnt[tid] = 0u;
    __syncthreads();

    int b = blockIdx.x / BPI, j = blockIdx.x % BPI;
    int n = j * 256 + tid;
    if (n < NN) {
        const float* row = conf + ((size_t)b * NN + n) * CC;
        const uf4* row4 = reinterpret_cast<const uf4*>(row);
        float r[CC];
        #pragma unroll
        for (int q = 0; q < 20; ++q) {
            floatx4 v = row4[q];
            r[4 * q] = v.x; r[4 * q + 1] = v.y; r[4 * q + 2] = v.z; r[4 * q + 3] = v.w;
        }
        r[80] = row[80];

        float mx = r[0];
        #pragma unroll
        for (int c = 1; c < CC; ++c) mx = fmaxf(mx, r[c]);   // max: order-independent, exact

        float s = 0.f;                                        // exact sequential sum, c = 0..80
        #pragma unroll
        for (int c = 0; c < CC; ++c) {
            r[c] = expf(__fsub_rn(r[c], mx));
            s = __fadd_rn(s, r[c]);
        }
        mxs[(size_t)b * NN + n] = make_float2(mx, s);

        float rcp = __builtin_amdgcn_rcpf(s);
        uint nn = (uint)n;
        #pragma unroll
        for (int c = 1; c < CC; ++c) {
            float p = __fmul_rn(r[c], rcp);
            if (p > SPECPF) {                      // ~1.5% of elements
                float sc = __fdiv_rn(r[c], s);     // exact score bits
                uint eb = __float_as_uint(sc);
                if (eb >= SPECBITS) {
                    uint pp = atomicAdd(&scnt[c - 1], 1u);
                    if (pp < CAPB) sbuf[(c - 1) * CAPB + pp] = (((ull)(~eb)) << 32) | nn;
                }
            }
        }
    }
    __syncthreads();

    // flush spec buffers: one global atomic per class per block, then coalesced copy
    if (tid < CM1) {
        uint c2 = scnt[tid];
        if (c2) {
            int bc = b * CM1 + tid;
            uint nstore = c2 > CAPB ? CAPB : c2;
            uint base = atomicAdd(ccnt + bc, nstore);
            if (c2 > CAPB || base + nstore > CAP2) ovf[bc] = 1u;
            uint lim = base + nstore; if (lim > CAP2) lim = CAP2;
            for (uint i = 0; base + i < lim; ++i)
                cand[(size_t)bc * CAP2 + base + i] = sbuf[tid * CAPB + i];
        }
    }
}

// ---- pass 2: per-(b,c) NMS with inline flag + inline exact fallback rescan ----
// flagged = !(ovf==0 && ccnt>=100): spec list provably complete iff >=100 untruncated members.
__global__ __launch_bounds__(256) void nms_kernel(const ull* __restrict__ cand,
                                                  const uint* __restrict__ ccnt,
                                                  const uint* __restrict__ ovf,
                                                  const float* __restrict__ conf,
                                                  const float2* __restrict__ mxs,
                                                  const float* __restrict__ loc,
                                                  const float* __restrict__ priors,
                                                  float* __restrict__ nms_scores,
                                                  float* __restrict__ nms_boxes) {
    int bc = blockIdx.x;
    int bimg = bc / CM1, ccls = bc % CM1;
    __shared__ ull arr[CAP2];                 // 16 KB
    __shared__ ull arr2[CAPS];                // 8 KB
    __shared__ uint hist[CBINS];
    __shared__ uint s_cut, s_mode, s_cnt2;
    __shared__ float bx[KTOP][4];
    __shared__ float sv[KTOP];
    __shared__ ull mlo[KTOP], mhi[KTOP];
    __shared__ ull keeplo, keephi;

    int tid = threadIdx.x;
    for (int i = tid; i < CBINS; i += 256) hist[i] = 0u;
    if (tid == 0) { s_cut = 0u; s_mode = 0u; s_cnt2 = 0u; }
    __syncthreads();

    uint rawcnt = ccnt[bc];
    bool flagged = !(ovf[bc] == 0u && rawcnt >= (uint)KTOP);
    int scc; ull* sorted;

    if (!flagged) {
        // ---- common path: load spec list, histogram, rank-Kt cut, compact ----
        int cc = (int)rawcnt; if (cc > CAP2) cc = CAP2;
        const ull* crow = cand + (size_t)bc * CAP2;
        for (int i = tid; i < cc; i += 256) {
            ull k = crow[i];
            arr[i] = k;
            uint bits = ~(uint)(k >> 32);
            uint bin = (bits - BASEBITS) >> CSHIFT;
            if (bin >= CBINS) bin = CBINS - 1;
            atomicAdd(&hist[bin], 1u);
        }
        __syncthreads();
        if (tid == 0) {
            uint Kt = (uint)(cc < KTOP ? cc : KTOP);
            if (Kt > 0) {
                uint cum = 0; int bb2 = 0;
                for (int i = CBINS - 1; i >= 0; --i) {
                    cum += hist[i];
                    if (cum >= Kt) { bb2 = i; break; }
                }
                if (cum <= CAPS) {
                    s_cut = BASEBITS + ((uint)bb2 << CSHIFT);
                    s_mode = 1u;
                }
            }
        }
        __syncthreads();
        if (s_mode) {
            uint cutv = s_cut;
            for (int i = tid; i < cc; i += 256) {
                ull k = arr[i];
                uint bits = ~(uint)(k >> 32);
                if (bits >= cutv) { uint p = atomicAdd(&s_cnt2, 1u); arr2[p] = k; }
            }
            __syncthreads();
            scc = (int)s_cnt2;
            sorted = arr2;
        } else {
            scc = cc;
            sorted = arr;
        }
    } else {
        // ---- rare path: exact self-contained column rescan (validated fallback logic) ----
        int c = ccls + 1;
        for (int n = tid; n < NN; n += 256) {
            float x = conf[((size_t)bimg * NN + n) * CC + c];
            float2 ms = mxs[(size_t)bimg * NN + n];
            float e = expf(__fsub_rn(x, ms.x));
            float sc = __fdiv_rn(e, ms.y);
            if (sc > 0.01f) {
                uint bits = __float_as_uint(sc);
                uint bin = (bits - BASEBITS) >> CSHIFT;
                if (bin >= CBINS) bin = CBINS - 1;
                atomicAdd(&hist[bin], 1u);
            }
        }
        __syncthreads();
        if (tid == 0) {
            uint total = 0;
            for (int i = 0; i < CBINS; ++i) total += hist[i];
            uint Kt = total < KTOP ? total : KTOP;
            s_cut = 0xFFFFFFFFu;
            if (Kt > 0) {
                uint cum = 0; int bb2 = 0;
                for (int i = CBINS - 1; i >= 0; --i) {
                    cum += hist[i];
                    if (cum >= Kt) { bb2 = i; break; }
                }
                uint cutbin = (cum <= CAP2) ? (uint)bb2 : (uint)(bb2 + 1);
                s_cut = BASEBITS + (cutbin << CSHIFT);
            }
        }
        __syncthreads();
        uint cutv = s_cut;
        for (int n = tid; n < NN; n += 256) {
            float x = conf[((size_t)bimg * NN + n) * CC + c];
            float2 ms = mxs[(size_t)bimg * NN + n];
            float e = expf(__fsub_rn(x, ms.x));
            float sc = __fdiv_rn(e, ms.y);
            if (sc > 0.01f) {
                uint bits = __float_as_uint(sc);
                if (bits >= cutv) {
                    uint p = atomicAdd(&s_cnt2, 1u);
                    if (p < CAP2) arr[p] = (((ull)(~bits)) << 32) | (uint)n;
                }
            }
        }
        __syncthreads();
        scc = (int)s_cnt2; if (scc > CAP2) scc = CAP2;
        sorted = arr;
    }

    int S = 1; while (S < scc) S <<= 1; if (S < 2) S = 2;
    for (int i = scc + tid; i < S; i += 256) sorted[i] = ~0ull;
    __syncthreads();

    for (int k = 2; k <= S; k <<= 1) {
        for (int jj = k >> 1; jj > 0; jj >>= 1) {
            for (int i = tid; i < S; i += 256) {
                int ixj = i ^ jj;
                if (ixj > i) {
                    ull a = sorted[i], b2 = sorted[ixj];
                    bool up = ((i & k) == 0);
                    if ((a > b2) == up) { sorted[i] = b2; sorted[ixj] = a; }
                }
            }
            __syncthreads();
        }
    }

    if (tid < KTOP) {
        float val = 0.f; uint n = 0;
        if (tid < scc) {
            ull kk = sorted[tid];
            val = __uint_as_float(~(uint)(kk >> 32));
            n = (uint)(kk & 0xFFFFFFFFu);
        }
        sv[tid] = val;
        float4 l = reinterpret_cast<const float4*>(loc)[(size_t)bimg * NN + n];
        float4 p = reinterpret_cast<const float4*>(priors)[n];
        float cx = __fadd_rn(__fmul_rn(__fmul_rn(l.x, 0.1f), p.z), p.x);
        float cy = __fadd_rn(__fmul_rn(__fmul_rn(l.y, 0.1f), p.w), p.y);
        float w  = __fmul_rn(expf(__fmul_rn(l.z, 0.2f)), p.z);
        float h  = __fmul_rn(expf(__fmul_rn(l.w, 0.2f)), p.w);
        bx[tid][0] = __fsub_rn(cx, __fmul_rn(w, 0.5f));
        bx[tid][1] = __fsub_rn(cy, __fmul_rn(h, 0.5f));
        bx[tid][2] = __fadd_rn(cx, __fmul_rn(w, 0.5f));
        bx[tid][3] = __fadd_rn(cy, __fmul_rn(h, 0.5f));
    }
    __syncthreads();

    if (tid < KTOP) {
        float x1 = bx[tid][0], y1 = bx[tid][1], x2 = bx[tid][2], y2 = bx[tid][3];
        float ai = __fmul_rn(fmaxf(__fsub_rn(x2, x1), 0.f), fmaxf(__fsub_rn(y2, y1), 0.f));
        ull lo = 0, hi = 0;
        for (int jj = 0; jj < KTOP; ++jj) {
            float jx1 = bx[jj][0], jy1 = bx[jj][1], jx2 = bx[jj][2], jy2 = bx[jj][3];
            float iw = fmaxf(__fsub_rn(fminf(x2, jx2), fmaxf(x1, jx1)), 0.f);
            float ih = fmaxf(__fsub_rn(fminf(y2, jy2), fmaxf(y1, jy1)), 0.f);
            float inter = __fmul_rn(iw, ih);
            float aj = __fmul_rn(fmaxf(__fsub_rn(jx2, jx1), 0.f), fmaxf(__fsub_rn(jy2, jy1), 0.f));
            float denom = __fadd_rn(__fsub_rn(__fadd_rn(ai, aj), inter), 1e-8f);
            float iou = __fdiv_rn(inter, denom);
            if (iou > 0.45f) { if (jj < 64) lo |= (1ull << jj); else hi |= (1ull << (jj - 64)); }
        }
        mlo[tid] = lo; mhi[tid] = hi;
    }
    __syncthreads();

    if (tid == 0) {
        ull klo = 0, khi = 0;
        for (int i = 0; i < KTOP; ++i) {
            ull sup = (mlo[i] & klo) | (mhi[i] & khi);
            bool kp = (sv[i] > 0.f) && (sup == 0ull);
            if (kp) { if (i < 64) klo |= (1ull << i); else khi |= (1ull << (i - 64)); }
        }
        keeplo = klo; keephi = khi;
    }
    __syncthreads();

    if (tid < KTOP) {
        bool kp = (tid < 64) ? ((keeplo >> tid) & 1ull) : ((keephi >> (tid - 64)) & 1ull);
        size_t obase = (size_t)bc * KTOP + tid;
        nms_scores[obase] = kp ? sv[tid] : 0.f;
        float4 o; o.x = bx[tid][0]; o.y = bx[tid][1]; o.z = bx[tid][2]; o.w = bx[tid][3];
        reinterpret_cast<float4*>(nms_boxes)[obase] = o;
    }
}

// ---- final top-100, stage A: per-(image,chunk) top-100 of 1000 ----
__global__ __launch_bounds__(256) void final_partial_kernel(const float* __restrict__ nms_scores,
                                                            ull* __restrict__ fkeys) {
    int blk = blockIdx.x;             // b*FCH + ch
    int b = blk / FCH, ch = blk % FCH;
    __shared__ ull arr[FPAD];         // 8 KB
    int tid = threadIdx.x;
    const float* srow = nms_scores + (size_t)b * (CM1 * KTOP) + ch * FCHN;
    for (int i = tid; i < FPAD; i += 256) {
        ull key;
        if (i < FCHN) {
            float s = srow[i];
            uint bits = (s > 0.f) ? __float_as_uint(s) : 0u;
            key = (((ull)(~bits)) << 32) | (uint)(ch * FCHN + i);   // global per-image idx
        } else key = ~0ull;
        arr[i] = key;
    }
    __syncthreads();
    for (int k = 2; k <= FPAD; k <<= 1) {
        for (int jj = k >> 1; jj > 0; jj >>= 1) {
            for (int i = tid; i < FPAD; i += 256) {
                int ixj = i ^ jj;
                if (ixj > i) {
                    ull a = arr[i], b2 = arr[ixj];
                    bool up = ((i & k) == 0);
                    if ((a > b2) == up) { arr[i] = b2; arr[ixj] = a; }
                }
            }
            __syncthreads();
        }
    }
    if (tid < KTOP)
        fkeys[(size_t)b * (FCH * KTOP) + ch * KTOP + tid] = arr[tid];
}

// ---- final top-100, stage B: merge 8x100 -> exact top-100, gather ----
__global__ __launch_bounds__(256) void final_merge_kernel(const ull* __restrict__ fkeys,
                                                          const float* __restrict__ nms_boxes,
                                                          float* __restrict__ out) {
    int b = blockIdx.x;
    __shared__ ull arr[FPAD];         // 8 KB
    int tid = threadIdx.x;
    const ull* krow = fkeys + (size_t)b * (FCH * KTOP);
    for (int i = tid; i < FPAD; i += 256)
        arr[i] = (i < FCH * KTOP) ? krow[i] : ~0ull;
    __syncthreads();
    for (int k = 2; k <= FPAD; k <<= 1) {
        for (int jj = k >> 1; jj > 0; jj >>= 1) {
            for (int i = tid; i < FPAD; i += 256) {
                int ixj = i ^ jj;
                if (ixj > i) {
                    ull a = arr[i], b2 = arr[ixj];
                    bool up = ((i & k) == 0);
                    if ((a > b2) == up) { arr[i] = b2; arr[ixj] = a; }
                }
            }
            __syncthreads();
        }
    }
    if (tid < MAXDET) {
        ull kk = arr[tid];
        uint hb = (uint)(kk >> 32);
        uint idx = (uint)(kk & 0xFFFFFFFFu);
        float val = __uint_as_float(~hb);     // zeros decode to 0.0f
        float4 b4 = reinterpret_cast<const float4*>(nms_boxes)[(size_t)b * (CM1 * KTOP) + idx];
        reinterpret_cast<float4*>(out)[(size_t)b * MAXDET + tid] = b4;
        out[BB * MAXDET * 4 + b * MAXDET + tid] = val;
        out[BB * MAXDET * 5 + b * MAXDET + tid] = (float)(idx / KTOP + 1);
    }
}

extern "C" void kernel_launch(void* const* d_in, const int* in_sizes, int n_in,
                              void* d_out, int out_size, void* d_ws, size_t ws_size,
                              hipStream_t stream) {
    const float* loc    = (const float*)d_in[0];
    const float* conf   = (const float*)d_in[1];
    const float* priors = (const float*)d_in[2];
    float* out = (float*)d_out;

    // workspace layout (16B-aligned chunks); ccnt/ovf are the zeroed pair (contiguous)
    char* ws = (char*)d_ws;
    float* nms_scores = (float*)ws;                                        // 1.02 MB
    float* nms_boxes  = nms_scores + (size_t)BB * CM1 * KTOP;              // 4.1 MB
    ull*   cand       = (ull*)(nms_boxes + (size_t)BB * CM1 * KTOP * 4);   // 41.9 MB
    float2* mxs       = (float2*)(cand + (size_t)BB * CM1 * CAP2);         // 6.3 MB
    ull*   fkeys      = (ull*)(mxs + (size_t)BB * NN);                     // 0.2 MB
    uint*  ccnt       = (uint*)(fkeys + (size_t)BB * FCH * KTOP);          // 2560 zeroed
    uint*  ovf        = ccnt + (size_t)BB * CM1;                           // 2560 zeroed

    zero_kernel<<<(BB * CM1 * 2 + 255) / 256, 256, 0, stream>>>(ccnt, BB * CM1 * 2);

    softmax_spec_kernel<<<BB * BPI, 256, 0, stream>>>(conf, mxs, cand, ccnt, ovf);
    nms_kernel<<<BB * CM1, 256, 0, stream>>>(cand, ccnt, ovf, conf, mxs, loc, priors,
                                             nms_scores, nms_boxes);
    final_partial_kernel<<<BB * FCH, 256, 0, stream>>>(nms_scores, fkeys);
    final_merge_kernel<<<BB, 256, 0, stream>>>(fkeys, nms_boxes, out);
}